// Round 26
// baseline (96.782 us; speedup 1.0000x reference)
//
#include <hip/hip_runtime.h>
#include <cstdint>

#define D_MODEL 768
#define NH      12
#define DKH     64
#define SEQ     2048
#define BS      2
#define MROWS   (BS*SEQ)   // 4096

typedef __bf16 bf16x8 __attribute__((ext_vector_type(8)));
typedef __bf16 bf16x4 __attribute__((ext_vector_type(4)));
typedef float  f32x4  __attribute__((ext_vector_type(4)));
typedef unsigned int u32_as1 __attribute__((address_space(1)));
typedef unsigned int u32_as3 __attribute__((address_space(3)));

__device__ __forceinline__ void gld16(const void* g, void* l) {
  __builtin_amdgcn_global_load_lds((const u32_as1*)g, (u32_as3*)l, 16, 0, 0);
}
__device__ __forceinline__ unsigned short f2bf(float x) {
  return __builtin_bit_cast(unsigned short, (__bf16)x);
}
// storage position of logical column c within each 64-block:
// c = 32k+16hi+4g+j -> p = 32k+8g+4hi+j (attn's contiguous fragment order)
__device__ __forceinline__ int permc64(int c) {
  return (c & ~63) | (c & 32) | ((c & 12) << 1) | ((c & 16) >> 2) | (c & 3);
}
// inverse: logical c held at storage position p (r17/r20-verified)
__device__ __forceinline__ int clog64(int p) {
  return (p & 32) | ((p & 4) << 2) | ((p & 24) >> 1) | (p & 3);
}

// ---------------- fused convert kernel (q, c, 4 weights) ---------------------
// blocks [0,3072): query ; [3072,6144): context ; [6144,8448): 4 weights.
// Section offsets via subtraction (3072 not a pow2!).
__global__ void cvt_all(
    const float* __restrict__ q, const float* __restrict__ c,
    const float* __restrict__ wq, const float* __restrict__ wk,
    const float* __restrict__ wv, const float* __restrict__ wf,
    unsigned short* __restrict__ oq, unsigned short* __restrict__ oc,
    unsigned short* __restrict__ owq, unsigned short* __restrict__ owk,
    unsigned short* __restrict__ owv, unsigned short* __restrict__ owf)
{
  const int b = blockIdx.x;
  const float* in; unsigned short* out; int i;
  if (b < 6144) {
    in = (b < 3072) ? q : c;
    out = (b < 3072) ? oq : oc;
    i = ((b < 3072) ? b : b - 3072) * 256 + threadIdx.x;
  } else {
    int wb = b - 6144, wi = wb / 576;
    in  = (wi == 0) ? wq : (wi == 1) ? wk : (wi == 2) ? wv : wf;
    out = (wi == 0) ? owq : (wi == 1) ? owk : (wi == 2) ? owv : owf;
    i = (wb - wi * 576) * 256 + threadIdx.x;
  }
  float4 v = reinterpret_cast<const float4*>(in)[i];
  ushort4 o; o.x = f2bf(v.x); o.y = f2bf(v.y); o.z = f2bf(v.z); o.w = f2bf(v.w);
  reinterpret_cast<ushort4*>(out)[i] = o;
}

// cmask (int) -> bf16 mask vector, stored COLUMN-PERMUTED (matches attn's
// contiguous fragment order). Scatter stays inside each 128B segment.
__global__ void mask_bf(const int* __restrict__ m, unsigned short* __restrict__ o) {
  int i = blockIdx.x * 256 + threadIdx.x;   // 4096 total
  o[permc64(i)] = f2bf(m[i] ? 1.0f : 0.0f);
}

// ---------------- 128x128 NT GEMM body (K=768), dbuf, 1 barrier/K-step ------
// r6-proven structure: 4 waves (2x2 of 64x64), BK=64, 64KB LDS (2 blocks/CU).
// 2x the staged-byte arithmetic intensity of the 64x64 body (the 64x64 shape
// sits at its known ~343TF structural ceiling; staging BW is the limiter).
// permB (literal at call site): read B-fragment row via clog64 so output
// position col holds logical column clog64(col&63); stores linear/coalesced.
template<bool OUT_F32>
__device__ __forceinline__ void gemm128_body(
    const unsigned short* __restrict__ A, const unsigned short* __restrict__ B,
    const float* __restrict__ bias, int biasRow, void* __restrict__ Cout,
    int ldc, int m0, int n0, float outScale, const int* __restrict__ colMask,
    int permB)
{
  __shared__ alignas(16) char sA[2][16384];   // 128 rows x 128B, XOR-swizzled
  __shared__ alignas(16) char sB[2][16384];
  const int tid = threadIdx.x;
  const int w = tid >> 6, l = tid & 63;
  const int g16 = l >> 4, c16 = l & 15;
  const int wr = (w >> 1) * 64, wc = (w & 1) * 64;

  auto stage = [&](const unsigned short* __restrict__ P, int p0, int kt, char* dst) {
#pragma unroll
    for (int i = 0; i < 4; i++) {
      int ch = w * 4 + i;                      // 16 chunks of 1KB
      int X = ch * 1024 + l * 16;
      int row = X >> 7;
      int sl = ((X >> 4) & 7) ^ (row & 7);     // inverse-swizzled source slot
      gld16(P + (size_t)(p0 + row) * 768 + kt + sl * 8, dst + ch * 1024);
    }
  };

  f32x4 acc[4][4];
#pragma unroll
  for (int m = 0; m < 4; m++)
#pragma unroll
    for (int n = 0; n < 4; n++) acc[m][n] = f32x4{0.f, 0.f, 0.f, 0.f};

  stage(A, m0, 0, sA[0]);
  stage(B, n0, 0, sB[0]);
  __syncthreads();
  int cur = 0;
  for (int kt = 0; kt < 768; kt += 64) {
    if (kt + 64 < 768) {
      stage(A, m0, kt + 64, sA[cur ^ 1]);
      stage(B, n0, kt + 64, sB[cur ^ 1]);
    }
    __builtin_amdgcn_s_setprio(1);
#pragma unroll
    for (int kk = 0; kk < 2; kk++) {
      bf16x8 af[4], bq[4];
#pragma unroll
      for (int m = 0; m < 4; m++) {
        int row = wr + m * 16 + c16, slot = kk * 4 + g16;
        af[m] = *(const bf16x8*)(sA[cur] + row * 128 + ((slot ^ (row & 7)) << 4));
      }
#pragma unroll
      for (int n = 0; n < 4; n++) {
        int off = wc + n * 16 + c16;            // local col 0..127
        if (permB) off = (off & ~63) | clog64(off & 63);
        int row = off, slot = kk * 4 + g16;
        bq[n] = *(const bf16x8*)(sB[cur] + row * 128 + ((slot ^ (row & 7)) << 4));
      }
#pragma unroll
      for (int m = 0; m < 4; m++)
#pragma unroll
        for (int n = 0; n < 4; n++)
          acc[m][n] = __builtin_amdgcn_mfma_f32_16x16x32_bf16(af[m], bq[n], acc[m][n], 0, 0, 0);
    }
    __builtin_amdgcn_s_setprio(0);
    __syncthreads();
    cur ^= 1;
  }

#pragma unroll
  for (int m = 0; m < 4; m++)
#pragma unroll
    for (int n = 0; n < 4; n++)
#pragma unroll
      for (int r = 0; r < 4; r++) {
        int row = m0 + wr + m * 16 + g16 * 4 + r;
        int col = n0 + wc + n * 16 + c16;
        float v = (acc[m][n][r] + (biasRow ? bias[row] : bias[col])) * outScale;
        if (colMask) {
          int cl = permB ? ((col & ~63) | clog64(col & 63)) : col;
          v *= (float)colMask[cl];
        }
        if constexpr (OUT_F32) ((float*)Cout)[(size_t)row * ldc + col] = v;
        else ((unsigned short*)Cout)[(size_t)row * ldc + col] = f2bf(v);
      }
}

// scale*log2(e) folded into Q so attn softmax uses raw v_exp_f32
#define QSCALE 0.1803368801111f   // 0.125 * log2(e)

// Fused QKV projections, 128x128 tiles: grid dim3(192, 3); x XCD-swizzled
// (192 = 24 x 8; 192*y = 0 mod 8 keeps x&7 = XCD). Three literal-arg call
// sites to ONE instantiation (shared 64KB LDS -- r17 trap avoided).
__global__ __launch_bounds__(256, 2) void gemm_qkv(
    const unsigned short* __restrict__ q_bf, const unsigned short* __restrict__ c_bf,
    const unsigned short* __restrict__ wq, const unsigned short* __restrict__ wk,
    const unsigned short* __restrict__ wv,
    const float* __restrict__ bq, const float* __restrict__ bk,
    const float* __restrict__ bv, const int* __restrict__ cmask,
    unsigned short* __restrict__ Qb, unsigned short* __restrict__ Kb,
    unsigned short* __restrict__ Vtb)
{
  const int x = blockIdx.x;
  const int lin = (x & 7) * 24 + (x >> 3);   // bijective 0..191
  if (blockIdx.y == 0) {
    gemm128_body<false>(q_bf, wq, bq, 0, Qb, 768, (lin / 6) * 128, (lin % 6) * 128,
                        QSCALE, nullptr, 0);
  } else if (blockIdx.y == 1) {
    gemm128_body<false>(c_bf, wk, bk, 0, Kb, 768, (lin / 6) * 128, (lin % 6) * 128,
                        1.0f, nullptr, 0);
  } else {
    // Vt[dv][c-storage]: position col holds logical c = clog64(col&63);
    // masked logical cols zeroed; stores linear/coalesced
    gemm128_body<false>(wv, c_bf, bv, 1, Vtb, 4096, (lin % 6) * 128, (lin / 6) * 128,
                        1.0f, cmask, 1);
  }
}

// ---------------- 64x64 NT GEMM body for fc (r22-proven) ---------------------
template<bool OUT_F32>
__device__ __forceinline__ void gemm64_body(
    const unsigned short* __restrict__ A, const unsigned short* __restrict__ B,
    const float* __restrict__ bias, void* __restrict__ Cout,
    int ldc, int m0, int n0)
{
  __shared__ alignas(16) char sA[2][8192];   // 64 rows x 128B, XOR-swizzled
  __shared__ alignas(16) char sB[2][8192];
  const int tid = threadIdx.x;
  const int w = tid >> 6, l = tid & 63;
  const int g16 = l >> 4, c16 = l & 15;
  const int wr = (w >> 1) * 32, wc = (w & 1) * 32;

  auto stage = [&](const unsigned short* __restrict__ P, int p0, int kt, char* dst) {
#pragma unroll
    for (int i = 0; i < 2; i++) {
      int ch = w * 2 + i;
      int X = ch * 1024 + l * 16;
      int row = X >> 7;
      int sl = ((X >> 4) & 7) ^ (row & 7);
      gld16(P + (size_t)(p0 + row) * 768 + kt + sl * 8, dst + ch * 1024);
    }
  };

  f32x4 acc[2][2];
#pragma unroll
  for (int m = 0; m < 2; m++)
#pragma unroll
    for (int n = 0; n < 2; n++) acc[m][n] = f32x4{0.f, 0.f, 0.f, 0.f};

  stage(A, m0, 0, sA[0]);
  stage(B, n0, 0, sB[0]);
  __syncthreads();
  int cur = 0;
  for (int kt = 0; kt < 768; kt += 64) {
    if (kt + 64 < 768) {
      stage(A, m0, kt + 64, sA[cur ^ 1]);
      stage(B, n0, kt + 64, sB[cur ^ 1]);
    }
    __builtin_amdgcn_s_setprio(1);
#pragma unroll
    for (int kk = 0; kk < 2; kk++) {
      bf16x8 af[2], bq[2];
#pragma unroll
      for (int m = 0; m < 2; m++) {
        int row = wr + m * 16 + c16, slot = kk * 4 + g16;
        af[m] = *(const bf16x8*)(sA[cur] + row * 128 + ((slot ^ (row & 7)) << 4));
      }
#pragma unroll
      for (int n = 0; n < 2; n++) {
        int row = wc + n * 16 + c16, slot = kk * 4 + g16;
        bq[n] = *(const bf16x8*)(sB[cur] + row * 128 + ((slot ^ (row & 7)) << 4));
      }
#pragma unroll
      for (int m = 0; m < 2; m++)
#pragma unroll
        for (int n = 0; n < 2; n++)
          acc[m][n] = __builtin_amdgcn_mfma_f32_16x16x32_bf16(af[m], bq[n], acc[m][n], 0, 0, 0);
    }
    __builtin_amdgcn_s_setprio(0);
    __syncthreads();
    cur ^= 1;
  }

#pragma unroll
  for (int m = 0; m < 2; m++)
#pragma unroll
    for (int n = 0; n < 2; n++)
#pragma unroll
      for (int r = 0; r < 4; r++) {
        int row = m0 + wr + m * 16 + g16 * 4 + r;
        int col = n0 + wc + n * 16 + c16;
        float v = acc[m][n][r] + bias[col];
        if constexpr (OUT_F32) ((float*)Cout)[(size_t)row * ldc + col] = v;
        else ((unsigned short*)Cout)[(size_t)row * ldc + col] = f2bf(v);
      }
}

// ---------------- 64x64 NT GEMM for fc (grid 768) ----------------------------
__global__ __launch_bounds__(256, 4) void gemm_fc64(
    const unsigned short* __restrict__ A, const unsigned short* __restrict__ B,
    const float* __restrict__ bias, float* __restrict__ Cout)
{
  const int flat = blockIdx.x;
  const int lin = (flat & 7) * 96 + (flat >> 3);
  const int tf = lin % 12, ts = lin / 12;
  gemm64_body<true>(A, B, bias, Cout, 768, ts * 64, tf * 64);
}

// ---------------- flash attention (r20/r22/r25, passing, byte-identical) -----
// In-register P via relabeled k-order; Vtb/maskbf column-permuted -> vf is one
// contiguous conflict-free b128, mfrag one 16B load.
__global__ __launch_bounds__(256, 4) void attn_kernel(
    const unsigned short* __restrict__ Qb, const unsigned short* __restrict__ Kb,
    const unsigned short* __restrict__ Vt, const unsigned short* __restrict__ maskbf,
    unsigned short* __restrict__ Ob)
{
  __shared__ alignas(16) char sK[2][8192];   // 64 x 64 bf16, swizzled rows
  __shared__ alignas(16) char sV[2][8192];   // 64(dv) x 64(c, permuted)
  const int tid = threadIdx.x, w = tid >> 6, l = tid & 63;
  const int g16 = l >> 4, c16 = l & 15;
  const int flat = blockIdx.x;                 // 768
  const int xcd = flat & 7, sidx = flat >> 3;  // sidx 0..95
  const int p = xcd + 8 * (sidx >> 5);         // panel 0..23
  const int qt = sidx & 31;
  const int h = p % 12, b = p / 12;
  const int qrow0 = b * SEQ + qt * 64;
  const int crow0 = b * SEQ;

  bf16x8 qa[2];
  {
    const unsigned short* qp =
        Qb + (size_t)(qrow0 + w * 16 + c16) * D_MODEL + h * DKH + g16 * 8;
    qa[0] = *(const bf16x8*)(qp);
    qa[1] = *(const bf16x8*)(qp + 32);
  }

  auto stageK = [&](int ct, int buf) {
#pragma unroll
    for (int i = 0; i < 2; i++) {
      int ch = w * 2 + i;
      int X = ch * 1024 + l * 16;
      int row = X >> 7;
      int sl = ((X >> 4) & 7) ^ (row & 7);
      gld16(Kb + (size_t)(crow0 + ct + row) * D_MODEL + h * DKH + sl * 8,
            sK[buf] + ch * 1024);
    }
  };
  auto stageV = [&](int ct, int buf) {
#pragma unroll
    for (int i = 0; i < 2; i++) {
      int ch = w * 2 + i;
      int X = ch * 1024 + l * 16;
      int row = X >> 7;
      int sl = ((X >> 4) & 7) ^ (row & 7);
      gld16(Vt + (size_t)(h * DKH + row) * (size_t)MROWS + crow0 + ct + sl * 8,
            sV[buf] + ch * 1024);
    }
  };

  f32x4 accO[4], accL;
#pragma unroll
  for (int n = 0; n < 4; n++) accO[n] = f32x4{0.f, 0.f, 0.f, 0.f};
  accL = f32x4{0.f, 0.f, 0.f, 0.f};

  stageK(0, 0); stageV(0, 0);
  __syncthreads();
  int cur = 0;

  for (int ct = 0; ct < SEQ; ct += 64) {
    if (ct + 64 < SEQ) { stageK(ct + 64, cur ^ 1); stageV(ct + 64, cur ^ 1); }

    // mask fragment: contiguous 16B (maskbf stored permuted by producer)
    bf16x8 mfrag[2];
#pragma unroll
    for (int kk = 0; kk < 2; kk++)
      mfrag[kk] = *(const bf16x8*)(maskbf + crow0 + ct + kk * 32 + g16 * 8);

    // S^T = K Q^T (r9-verified): s4[n][r] = S[c = 16n+4g+r][q = w*16+c16]
    f32x4 s4[4];
#pragma unroll
    for (int n = 0; n < 4; n++) s4[n] = f32x4{0.f, 0.f, 0.f, 0.f};
    __builtin_amdgcn_s_setprio(1);
#pragma unroll
    for (int kk = 0; kk < 2; kk++) {
      bf16x8 kf[4];
#pragma unroll
      for (int n = 0; n < 4; n++) {
        int row = n * 16 + c16, slot = kk * 4 + g16;
        kf[n] = *(const bf16x8*)(sK[cur] + row * 128 + ((slot ^ (row & 7)) << 4));
      }
#pragma unroll
      for (int n = 0; n < 4; n++)
        s4[n] = __builtin_amdgcn_mfma_f32_16x16x32_bf16(kf[n], qa[kk], s4[n], 0, 0, 0);
    }
    __builtin_amdgcn_s_setprio(0);

    // p = exp2(s) in registers; lane-local A-frag pack (k-order
    // c(g,j) = 32kk + 16*(j>>2) + 4g + (j&3))
    bf16x8 paf[2];
#pragma unroll
    for (int kk = 0; kk < 2; kk++)
#pragma unroll
      for (int j = 0; j < 4; j++) {
        paf[kk][j]     = (__bf16)__builtin_amdgcn_exp2f(s4[2 * kk][j]);
        paf[kk][j + 4] = (__bf16)__builtin_amdgcn_exp2f(s4[2 * kk + 1][j]);
      }

    // O += P * V(masked, permuted) ; L += P * maskfrag.
    __builtin_amdgcn_s_setprio(1);
#pragma unroll
    for (int kk = 0; kk < 2; kk++) {
#pragma unroll
      for (int n = 0; n < 4; n++) {
        int row = n * 16 + c16, slot = kk * 4 + g16;
        bf16x8 vf = *(const bf16x8*)(sV[cur] + row * 128 + ((slot ^ (row & 7)) << 4));
        accO[n] = __builtin_amdgcn_mfma_f32_16x16x32_bf16(paf[kk], vf, accO[n], 0, 0, 0);
      }
      accL = __builtin_amdgcn_mfma_f32_16x16x32_bf16(paf[kk], mfrag[kk], accL, 0, 0, 0);
    }
    __builtin_amdgcn_s_setprio(0);

    __syncthreads();
    cur ^= 1;
  }

#pragma unroll
  for (int r = 0; r < 4; r++) {
    float inv = 1.0f / accL[r];
#pragma unroll
    for (int n = 0; n < 4; n++) {
      int row = qrow0 + w * 16 + g16 * 4 + r;
      int col = h * DKH + n * 16 + c16;
      Ob[(size_t)row * D_MODEL + col] = f2bf(accO[n][r] * inv);
    }
  }
}

// ---------------- launcher --------------------------------------------------
extern "C" void kernel_launch(void* const* d_in, const int* in_sizes, int n_in,
                              void* d_out, int out_size, void* d_ws, size_t ws_size,
                              hipStream_t stream) {
  const float* query   = (const float*)d_in[0];
  const float* context = (const float*)d_in[1];
  const int*   cmask   = (const int*)d_in[2];
  const float* Wq_w = (const float*)d_in[3];
  const float* Wq_b = (const float*)d_in[4];
  const float* Wk_w = (const float*)d_in[5];
  const float* Wk_b = (const float*)d_in[6];
  const float* Wv_w = (const float*)d_in[7];
  const float* Wv_b = (const float*)d_in[8];
  const float* fc_w = (const float*)d_in[9];
  const float* fc_b = (const float*)d_in[10];
  float* out = (float*)d_out;

  unsigned short* ws   = (unsigned short*)d_ws;
  const size_t NQ = (size_t)MROWS * D_MODEL;
  const size_t NW = (size_t)D_MODEL * D_MODEL;
  unsigned short* q_bf = ws;
  unsigned short* c_bf = q_bf + NQ;
  unsigned short* Qb   = c_bf + NQ;
  unsigned short* Kb   = Qb + NQ;
  unsigned short* Vtb  = Kb + NQ;
  unsigned short* Ob   = Vtb + NQ;
  unsigned short* wq   = Ob + NQ;
  unsigned short* wk   = wq + NW;
  unsigned short* wv   = wk + NW;
  unsigned short* wf   = wv + NW;
  // q_bf is dead after gemm_qkv; reuse its head for the bf16 mask vector
  unsigned short* maskbf = q_bf;   // 4096 bf16 = 8KB

  // one fused convert launch: q, c, 4 weights
  cvt_all<<<8448, 256, 0, stream>>>(query, context, Wq_w, Wk_w, Wv_w, fc_w,
                                    q_bf, c_bf, wq, wk, wv, wf);

  // Q/K/V projections fused, 128x128 tiles: y=0 Q(scaled), y=1 K,
  // y=2 V^T(masked, perm-read -> permuted storage)
  gemm_qkv<<<dim3(192, 3), 256, 0, stream>>>(
      q_bf, c_bf, wq, wk, wv, Wq_b, Wk_b, Wv_b, cmask, Qb, Kb, Vtb);

  // after gemm_qkv, q_bf is dead -> safe to overwrite with (permuted) maskbf
  mask_bf<<<MROWS / 256, 256, 0, stream>>>(cmask, maskbf);

  attn_kernel<<<768, 256, 0, stream>>>(Qb, Kb, Vtb, maskbf, Ob);

  // out = O @ fc^T + fb (f32), 64x64 tiles, grid 768
  gemm_fc64<<<768, 256, 0, stream>>>(Ob, wf, fc_b, out);
}

// Round 27
// 87.963 us; speedup vs baseline: 1.1003x; 1.1003x over previous
//
#include <hip/hip_runtime.h>
#include <cstdint>

#define D_MODEL 768
#define NH      12
#define DKH     64
#define SEQ     2048
#define BS      2
#define MROWS   (BS*SEQ)   // 4096

typedef __bf16 bf16x8 __attribute__((ext_vector_type(8)));
typedef __bf16 bf16x4 __attribute__((ext_vector_type(4)));
typedef float  f32x4  __attribute__((ext_vector_type(4)));
typedef unsigned int u32_as1 __attribute__((address_space(1)));
typedef unsigned int u32_as3 __attribute__((address_space(3)));

__device__ __forceinline__ void gld16(const void* g, void* l) {
  __builtin_amdgcn_global_load_lds((const u32_as1*)g, (u32_as3*)l, 16, 0, 0);
}
__device__ __forceinline__ unsigned short f2bf(float x) {
  return __builtin_bit_cast(unsigned short, (__bf16)x);
}
// storage position of logical column c within each 64-block:
// c = 32k+16hi+4g+j -> p = 32k+8g+4hi+j (attn's contiguous fragment order)
__device__ __forceinline__ int permc64(int c) {
  return (c & ~63) | (c & 32) | ((c & 12) << 1) | ((c & 16) >> 2) | (c & 3);
}
// inverse: logical c held at storage position p (r17/r20-verified)
__device__ __forceinline__ int clog64(int p) {
  return (p & 32) | ((p & 4) << 2) | ((p & 24) >> 1) | (p & 3);
}

// ---------------- fused convert kernel (q, c, 4 weights) ---------------------
// blocks [0,3072): query ; [3072,6144): context ; [6144,8448): 4 weights.
// Section offsets via subtraction (3072 not a pow2!).
__global__ void cvt_all(
    const float* __restrict__ q, const float* __restrict__ c,
    const float* __restrict__ wq, const float* __restrict__ wk,
    const float* __restrict__ wv, const float* __restrict__ wf,
    unsigned short* __restrict__ oq, unsigned short* __restrict__ oc,
    unsigned short* __restrict__ owq, unsigned short* __restrict__ owk,
    unsigned short* __restrict__ owv, unsigned short* __restrict__ owf)
{
  const int b = blockIdx.x;
  const float* in; unsigned short* out; int i;
  if (b < 6144) {
    in = (b < 3072) ? q : c;
    out = (b < 3072) ? oq : oc;
    i = ((b < 3072) ? b : b - 3072) * 256 + threadIdx.x;
  } else {
    int wb = b - 6144, wi = wb / 576;
    in  = (wi == 0) ? wq : (wi == 1) ? wk : (wi == 2) ? wv : wf;
    out = (wi == 0) ? owq : (wi == 1) ? owk : (wi == 2) ? owv : owf;
    i = (wb - wi * 576) * 256 + threadIdx.x;
  }
  float4 v = reinterpret_cast<const float4*>(in)[i];
  ushort4 o; o.x = f2bf(v.x); o.y = f2bf(v.y); o.z = f2bf(v.z); o.w = f2bf(v.w);
  reinterpret_cast<ushort4*>(out)[i] = o;
}

// cmask (int) -> bf16 mask vector, stored COLUMN-PERMUTED (matches attn's
// contiguous fragment order). Scatter stays inside each 128B segment.
__global__ void mask_bf(const int* __restrict__ m, unsigned short* __restrict__ o) {
  int i = blockIdx.x * 256 + threadIdx.x;   // 4096 total
  o[permc64(i)] = f2bf(m[i] ? 1.0f : 0.0f);
}

// ---------------- 64x64 NT GEMM body (K=768), dbuf, 1 barrier/K-step --------
// At the 64^2-structure ceiling (~345 TF measured == m-ladder's 343): all
// alternatives measured worse (64x128 r15-21, 128^2 r16/r26, counted-vmcnt
// r23, unfused r24). C[m,n] = (sum_k A[m,k]*B[n,k] + bias)*outScale*mask.
// permB (literal at call site): read B-fragment row via clog64 so output
// position col holds logical column clog64(col&63); stores linear/coalesced.
template<bool OUT_F32>
__device__ __forceinline__ void gemm64_body(
    const unsigned short* __restrict__ A, const unsigned short* __restrict__ B,
    const float* __restrict__ bias, int biasRow, void* __restrict__ Cout,
    int ldc, int m0, int n0, float outScale, const int* __restrict__ colMask,
    int permB)
{
  __shared__ alignas(16) char sA[2][8192];   // 64 rows x 128B, XOR-swizzled
  __shared__ alignas(16) char sB[2][8192];
  const int tid = threadIdx.x;
  const int w = tid >> 6, l = tid & 63;
  const int g16 = l >> 4, c16 = l & 15;
  const int wr = (w >> 1) * 32, wc = (w & 1) * 32;

  auto stage = [&](const unsigned short* __restrict__ P, int p0, int kt, char* dst) {
#pragma unroll
    for (int i = 0; i < 2; i++) {
      int ch = w * 2 + i;
      int X = ch * 1024 + l * 16;
      int row = X >> 7;
      int sl = ((X >> 4) & 7) ^ (row & 7);
      gld16(P + (size_t)(p0 + row) * 768 + kt + sl * 8, dst + ch * 1024);
    }
  };

  f32x4 acc[2][2];
#pragma unroll
  for (int m = 0; m < 2; m++)
#pragma unroll
    for (int n = 0; n < 2; n++) acc[m][n] = f32x4{0.f, 0.f, 0.f, 0.f};

  stage(A, m0, 0, sA[0]);
  stage(B, n0, 0, sB[0]);
  __syncthreads();
  int cur = 0;
  for (int kt = 0; kt < 768; kt += 64) {
    if (kt + 64 < 768) {
      stage(A, m0, kt + 64, sA[cur ^ 1]);
      stage(B, n0, kt + 64, sB[cur ^ 1]);
    }
    __builtin_amdgcn_s_setprio(1);
#pragma unroll
    for (int kk = 0; kk < 2; kk++) {
      bf16x8 af[2], bq[2];
#pragma unroll
      for (int m = 0; m < 2; m++) {
        int row = wr + m * 16 + c16, slot = kk * 4 + g16;
        af[m] = *(const bf16x8*)(sA[cur] + row * 128 + ((slot ^ (row & 7)) << 4));
      }
#pragma unroll
      for (int n = 0; n < 2; n++) {
        int off = wc + n * 16 + c16;           // local col 0..63
        if (permB) off = clog64(off);
        int row = off, slot = kk * 4 + g16;
        bq[n] = *(const bf16x8*)(sB[cur] + row * 128 + ((slot ^ (row & 7)) << 4));
      }
#pragma unroll
      for (int m = 0; m < 2; m++)
#pragma unroll
        for (int n = 0; n < 2; n++)
          acc[m][n] = __builtin_amdgcn_mfma_f32_16x16x32_bf16(af[m], bq[n], acc[m][n], 0, 0, 0);
    }
    __builtin_amdgcn_s_setprio(0);
    __syncthreads();
    cur ^= 1;
  }

#pragma unroll
  for (int m = 0; m < 2; m++)
#pragma unroll
    for (int n = 0; n < 2; n++)
#pragma unroll
      for (int r = 0; r < 4; r++) {
        int row = m0 + wr + m * 16 + g16 * 4 + r;
        int col = n0 + wc + n * 16 + c16;
        float v = (acc[m][n][r] + (biasRow ? bias[row] : bias[col])) * outScale;
        if (colMask) {
          int cl = permB ? ((col & ~63) | clog64(col & 63)) : col;
          v *= (float)colMask[cl];
        }
        if constexpr (OUT_F32) ((float*)Cout)[(size_t)row * ldc + col] = v;
        else ((unsigned short*)Cout)[(size_t)row * ldc + col] = f2bf(v);
      }
}

// scale*log2(e) folded into Q so attn softmax uses raw v_exp_f32
#define QSCALE 0.1803368801111f   // 0.125 * log2(e)

// Fused QKV projections, 64x64 tiles: grid dim3(768, 3) = 2304 blocks.
// x XCD-swizzled (768 = 96 x 8). Three literal-arg call sites to ONE
// instantiation (shared 32KB LDS).
__global__ __launch_bounds__(256, 4) void gemm_qkv(
    const unsigned short* __restrict__ q_bf, const unsigned short* __restrict__ c_bf,
    const unsigned short* __restrict__ wq, const unsigned short* __restrict__ wk,
    const unsigned short* __restrict__ wv,
    const float* __restrict__ bq, const float* __restrict__ bk,
    const float* __restrict__ bv, const int* __restrict__ cmask,
    unsigned short* __restrict__ Qb, unsigned short* __restrict__ Kb,
    unsigned short* __restrict__ Vtb)
{
  const int x = blockIdx.x;
  const int lin = (x & 7) * 96 + (x >> 3);   // bijective 0..767
  if (blockIdx.y == 0) {
    gemm64_body<false>(q_bf, wq, bq, 0, Qb, 768, (lin / 12) * 64, (lin % 12) * 64,
                       QSCALE, nullptr, 0);
  } else if (blockIdx.y == 1) {
    gemm64_body<false>(c_bf, wk, bk, 0, Kb, 768, (lin / 12) * 64, (lin % 12) * 64,
                       1.0f, nullptr, 0);
  } else {
    // Vt[dv][c-storage]: position col holds logical c = clog64(col&63);
    // masked logical cols zeroed; stores linear/coalesced
    gemm64_body<false>(wv, c_bf, bv, 1, Vtb, 4096, (lin % 12) * 64, (lin / 12) * 64,
                       1.0f, cmask, 1);
  }
}

// ---------------- 64x64 NT GEMM for fc (grid 768) ----------------------------
__global__ __launch_bounds__(256, 4) void gemm_fc64(
    const unsigned short* __restrict__ A, const unsigned short* __restrict__ B,
    const float* __restrict__ bias, float* __restrict__ Cout)
{
  const int flat = blockIdx.x;
  const int lin = (flat & 7) * 96 + (flat >> 3);
  const int tf = lin % 12, ts = lin / 12;
  gemm64_body<true>(A, B, bias, 0, Cout, 768, ts * 64, tf * 64,
                    1.0f, nullptr, 0);
}

// ---------------- flash attention (r20/r22/r25, passing, byte-identical) -----
// In-register P via relabeled k-order; Vtb/maskbf column-permuted -> vf is one
// contiguous conflict-free b128, mfrag one 16B load. No-max softmax (scale in
// Q, exp2 direct); mask via zeroed Vt cols (accO) + bf16 mask frag (accL).
__global__ __launch_bounds__(256, 4) void attn_kernel(
    const unsigned short* __restrict__ Qb, const unsigned short* __restrict__ Kb,
    const unsigned short* __restrict__ Vt, const unsigned short* __restrict__ maskbf,
    unsigned short* __restrict__ Ob)
{
  __shared__ alignas(16) char sK[2][8192];   // 64 x 64 bf16, swizzled rows
  __shared__ alignas(16) char sV[2][8192];   // 64(dv) x 64(c, permuted)
  const int tid = threadIdx.x, w = tid >> 6, l = tid & 63;
  const int g16 = l >> 4, c16 = l & 15;
  const int flat = blockIdx.x;                 // 768
  const int xcd = flat & 7, sidx = flat >> 3;  // sidx 0..95
  const int p = xcd + 8 * (sidx >> 5);         // panel 0..23
  const int qt = sidx & 31;
  const int h = p % 12, b = p / 12;
  const int qrow0 = b * SEQ + qt * 64;
  const int crow0 = b * SEQ;

  bf16x8 qa[2];
  {
    const unsigned short* qp =
        Qb + (size_t)(qrow0 + w * 16 + c16) * D_MODEL + h * DKH + g16 * 8;
    qa[0] = *(const bf16x8*)(qp);
    qa[1] = *(const bf16x8*)(qp + 32);
  }

  auto stageK = [&](int ct, int buf) {
#pragma unroll
    for (int i = 0; i < 2; i++) {
      int ch = w * 2 + i;
      int X = ch * 1024 + l * 16;
      int row = X >> 7;
      int sl = ((X >> 4) & 7) ^ (row & 7);
      gld16(Kb + (size_t)(crow0 + ct + row) * D_MODEL + h * DKH + sl * 8,
            sK[buf] + ch * 1024);
    }
  };
  auto stageV = [&](int ct, int buf) {
#pragma unroll
    for (int i = 0; i < 2; i++) {
      int ch = w * 2 + i;
      int X = ch * 1024 + l * 16;
      int row = X >> 7;
      int sl = ((X >> 4) & 7) ^ (row & 7);
      gld16(Vt + (size_t)(h * DKH + row) * (size_t)MROWS + crow0 + ct + sl * 8,
            sV[buf] + ch * 1024);
    }
  };

  f32x4 accO[4], accL;
#pragma unroll
  for (int n = 0; n < 4; n++) accO[n] = f32x4{0.f, 0.f, 0.f, 0.f};
  accL = f32x4{0.f, 0.f, 0.f, 0.f};

  stageK(0, 0); stageV(0, 0);
  __syncthreads();
  int cur = 0;

  for (int ct = 0; ct < SEQ; ct += 64) {
    if (ct + 64 < SEQ) { stageK(ct + 64, cur ^ 1); stageV(ct + 64, cur ^ 1); }

    // mask fragment: contiguous 16B (maskbf stored permuted by producer)
    bf16x8 mfrag[2];
#pragma unroll
    for (int kk = 0; kk < 2; kk++)
      mfrag[kk] = *(const bf16x8*)(maskbf + crow0 + ct + kk * 32 + g16 * 8);

    // S^T = K Q^T (r9-verified): s4[n][r] = S[c = 16n+4g+r][q = w*16+c16]
    f32x4 s4[4];
#pragma unroll
    for (int n = 0; n < 4; n++) s4[n] = f32x4{0.f, 0.f, 0.f, 0.f};
    __builtin_amdgcn_s_setprio(1);
#pragma unroll
    for (int kk = 0; kk < 2; kk++) {
      bf16x8 kf[4];
#pragma unroll
      for (int n = 0; n < 4; n++) {
        int row = n * 16 + c16, slot = kk * 4 + g16;
        kf[n] = *(const bf16x8*)(sK[cur] + row * 128 + ((slot ^ (row & 7)) << 4));
      }
#pragma unroll
      for (int n = 0; n < 4; n++)
        s4[n] = __builtin_amdgcn_mfma_f32_16x16x32_bf16(kf[n], qa[kk], s4[n], 0, 0, 0);
    }
    __builtin_amdgcn_s_setprio(0);

    // p = exp2(s) in registers; lane-local A-frag pack (k-order
    // c(g,j) = 32kk + 16*(j>>2) + 4g + (j&3))
    bf16x8 paf[2];
#pragma unroll
    for (int kk = 0; kk < 2; kk++)
#pragma unroll
      for (int j = 0; j < 4; j++) {
        paf[kk][j]     = (__bf16)__builtin_amdgcn_exp2f(s4[2 * kk][j]);
        paf[kk][j + 4] = (__bf16)__builtin_amdgcn_exp2f(s4[2 * kk + 1][j]);
      }

    // O += P * V(masked, permuted) ; L += P * maskfrag.
    __builtin_amdgcn_s_setprio(1);
#pragma unroll
    for (int kk = 0; kk < 2; kk++) {
#pragma unroll
      for (int n = 0; n < 4; n++) {
        int row = n * 16 + c16, slot = kk * 4 + g16;
        bf16x8 vf = *(const bf16x8*)(sV[cur] + row * 128 + ((slot ^ (row & 7)) << 4));
        accO[n] = __builtin_amdgcn_mfma_f32_16x16x32_bf16(paf[kk], vf, accO[n], 0, 0, 0);
      }
      accL = __builtin_amdgcn_mfma_f32_16x16x32_bf16(paf[kk], mfrag[kk], accL, 0, 0, 0);
    }
    __builtin_amdgcn_s_setprio(0);

    __syncthreads();
    cur ^= 1;
  }

#pragma unroll
  for (int r = 0; r < 4; r++) {
    float inv = 1.0f / accL[r];
#pragma unroll
    for (int n = 0; n < 4; n++) {
      int row = qrow0 + w * 16 + g16 * 4 + r;
      int col = h * DKH + n * 16 + c16;
      Ob[(size_t)row * D_MODEL + col] = f2bf(accO[n][r] * inv);
    }
  }
}

// ---------------- launcher --------------------------------------------------
extern "C" void kernel_launch(void* const* d_in, const int* in_sizes, int n_in,
                              void* d_out, int out_size, void* d_ws, size_t ws_size,
                              hipStream_t stream) {
  const float* query   = (const float*)d_in[0];
  const float* context = (const float*)d_in[1];
  const int*   cmask   = (const int*)d_in[2];
  const float* Wq_w = (const float*)d_in[3];
  const float* Wq_b = (const float*)d_in[4];
  const float* Wk_w = (const float*)d_in[5];
  const float* Wk_b = (const float*)d_in[6];
  const float* Wv_w = (const float*)d_in[7];
  const float* Wv_b = (const float*)d_in[8];
  const float* fc_w = (const float*)d_in[9];
  const float* fc_b = (const float*)d_in[10];
  float* out = (float*)d_out;

  unsigned short* ws   = (unsigned short*)d_ws;
  const size_t NQ = (size_t)MROWS * D_MODEL;
  const size_t NW = (size_t)D_MODEL * D_MODEL;
  unsigned short* q_bf = ws;
  unsigned short* c_bf = q_bf + NQ;
  unsigned short* Qb   = c_bf + NQ;
  unsigned short* Kb   = Qb + NQ;
  unsigned short* Vtb  = Kb + NQ;
  unsigned short* Ob   = Vtb + NQ;
  unsigned short* wq   = Ob + NQ;
  unsigned short* wk   = wq + NW;
  unsigned short* wv   = wk + NW;
  unsigned short* wf   = wv + NW;
  // q_bf is dead after gemm_qkv; reuse its head for the bf16 mask vector
  unsigned short* maskbf = q_bf;   // 4096 bf16 = 8KB

  // one fused convert launch: q, c, 4 weights
  cvt_all<<<8448, 256, 0, stream>>>(query, context, Wq_w, Wk_w, Wv_w, fc_w,
                                    q_bf, c_bf, wq, wk, wv, wf);

  // Q/K/V projections fused, 64x64 tiles: y=0 Q(scaled), y=1 K,
  // y=2 V^T(masked, perm-read -> permuted storage)
  gemm_qkv<<<dim3(768, 3), 256, 0, stream>>>(
      q_bf, c_bf, wq, wk, wv, Wq_b, Wk_b, Wv_b, cmask, Qb, Kb, Vtb);

  // after gemm_qkv, q_bf is dead -> safe to overwrite with (permuted) maskbf
  mask_bf<<<MROWS / 256, 256, 0, stream>>>(cmask, maskbf);

  attn_kernel<<<768, 256, 0, stream>>>(Qb, Kb, Vtb, maskbf, Ob);

  // out = O @ fc^T + fb (f32), 64x64 tiles, grid 768
  gemm_fc64<<<768, 256, 0, stream>>>(Ob, wf, fc_b, out);
}